// Round 2
// baseline (388.591 us; speedup 1.0000x reference)
//
#include <hip/hip_runtime.h>

#define NUM_CLASSES 5
#define BATCH 4
#define NPB (64 * 256 * 256)            // voxels per batch = 4,194,304
#define VEC_PER_BATCH (NPB / 4)         // int4 vectors per batch = 1,048,576
#define THREADS 256
#define VECS_PER_THREAD 8               // 32 voxels per thread
#define BLOCKS_X (VEC_PER_BATCH / (THREADS * VECS_PER_THREAD))  // 512
#define TOTAL_BLOCKS (BLOCKS_X * BATCH) // 2048
#define SLOTS 15                        // per batch: 5 pred, 5 targ, 5 inter
// d_ws layout: cnt[0..59] = [b][slot], cnt[60] = completion ticket

__global__ __launch_bounds__(THREADS) void dice_fused_kernel(
    const int* __restrict__ pred, const int* __restrict__ targ,
    unsigned int* __restrict__ cnt, float* __restrict__ out) {
  const int b = blockIdx.y;
  const int4* __restrict__ p4 = (const int4*)(pred + (long long)b * NPB);
  const int4* __restrict__ t4 = (const int4*)(targ + (long long)b * NPB);

  // Block reads a contiguous 32 KB region per input: 8 iters x 4 KB.
  const int base = blockIdx.x * (THREADS * VECS_PER_THREAD);

  // Wave-uniform accumulators -> SGPRs. Classes 0..3 counted; class 4 by residual.
  unsigned int pc[4] = {0, 0, 0, 0};
  unsigned int tc[4] = {0, 0, 0, 0};
  unsigned int ic[4] = {0, 0, 0, 0};
  unsigned int eqc = 0;

#define ACC_ELEM(PE, TE)                                                  \
  {                                                                       \
    const int pe = (PE), te = (TE);                                       \
    eqc += __popcll(__builtin_amdgcn_ballot_w64(pe == te));               \
    _Pragma("unroll")                                                     \
    for (int c = 0; c < 4; ++c) {                                         \
      unsigned long long mp = __builtin_amdgcn_ballot_w64(pe == c);       \
      unsigned long long mt = __builtin_amdgcn_ballot_w64(te == c);       \
      pc[c] += (unsigned)__popcll(mp);                                    \
      tc[c] += (unsigned)__popcll(mt);                                    \
      ic[c] += (unsigned)__popcll(mp & mt);                               \
    }                                                                     \
  }

#pragma unroll
  for (int k = 0; k < VECS_PER_THREAD; ++k) {
    const int idx = base + k * THREADS + threadIdx.x;
    const int4 pv = p4[idx];
    const int4 tv = t4[idx];
    ACC_ELEM(pv.x, tv.x)
    ACC_ELEM(pv.y, tv.y)
    ACC_ELEM(pv.z, tv.z)
    ACC_ELEM(pv.w, tv.w)
  }

  // Per-wave voxel total (all lanes always active): 64 lanes * 32 voxels.
  const unsigned int V = 64u * VECS_PER_THREAD * 4u;

  __shared__ unsigned int s[SLOTS];
  __shared__ unsigned int done;
  if (threadIdx.x < SLOTS) s[threadIdx.x] = 0;
  __syncthreads();

  const int lane = threadIdx.x & 63;
  if (lane == 0) {
    unsigned int psum = 0, tsum = 0, isum = 0;
#pragma unroll
    for (int c = 0; c < 4; ++c) {
      atomicAdd(&s[c], pc[c]);
      atomicAdd(&s[5 + c], tc[c]);
      atomicAdd(&s[10 + c], ic[c]);
      psum += pc[c]; tsum += tc[c]; isum += ic[c];
    }
    atomicAdd(&s[4], V - psum);
    atomicAdd(&s[9], V - tsum);
    atomicAdd(&s[14], eqc - isum);
  }
  __syncthreads();

  if (threadIdx.x < SLOTS)
    atomicAdd(&cnt[b * SLOTS + threadIdx.x], s[threadIdx.x]);

  // Completion ticket; last block computes the 5 outputs.
  __threadfence();
  __syncthreads();
  if (threadIdx.x == 0) done = atomicAdd(&cnt[BATCH * SLOTS], 1u);
  __syncthreads();

  if (done == TOTAL_BLOCKS - 1 && threadIdx.x < NUM_CLASSES) {
    const int c = threadIdx.x;
    float acc = 0.0f;
#pragma unroll
    for (int bb = 0; bb < BATCH; ++bb) {
      const float ps = (float)atomicAdd(&cnt[bb * SLOTS + c], 0u);
      const float ts = (float)atomicAdd(&cnt[bb * SLOTS + 5 + c], 0u);
      const float is = (float)atomicAdd(&cnt[bb * SLOTS + 10 + c], 0u);
      float num = 2.0f * is;
      float den = ps + ts;
      if (den == 0.0f) { num = 1.0f; den = 1.0f; }
      acc += num / den;
    }
    out[c] = acc * (1.0f / BATCH);
  }
}

extern "C" void kernel_launch(void* const* d_in, const int* in_sizes, int n_in,
                              void* d_out, int out_size, void* d_ws, size_t ws_size,
                              hipStream_t stream) {
  const int* pred = (const int*)d_in[0];
  const int* targ = (const int*)d_in[1];
  float* out = (float*)d_out;
  unsigned int* cnt = (unsigned int*)d_ws;

  hipMemsetAsync(cnt, 0, (BATCH * SLOTS + 1) * sizeof(unsigned int), stream);

  dim3 grid(BLOCKS_X, BATCH);
  dice_fused_kernel<<<grid, THREADS, 0, stream>>>(pred, targ, cnt, out);
}

// Round 3
// 149.420 us; speedup vs baseline: 2.6007x; 2.6007x over previous
//
#include <hip/hip_runtime.h>

#define NUM_CLASSES 5
#define BATCH 4
#define NPB (64 * 256 * 256)            // voxels per batch = 4,194,304
#define VEC_PER_BATCH (NPB / 4)         // int4 vectors per batch = 1,048,576
#define THREADS 256
#define VECS_PER_THREAD 8               // 32 voxels per thread (max 63 for 6-bit fields)
#define BLOCKS_X (VEC_PER_BATCH / (THREADS * VECS_PER_THREAD))  // 512
#define SLOTS 15                        // per batch: 5 pred, 5 targ, 5 inter

// Packed per-lane counters: class c occupies bits [6c, 6c+6). 5*6=30 bits.
// Per-thread per-class count <= 32 voxels -> fits 6 bits.

__global__ __launch_bounds__(THREADS, 8) void dice_count_kernel(
    const int* __restrict__ pred, const int* __restrict__ targ,
    unsigned int* __restrict__ cnt) {
  const int b = blockIdx.y;
  const int4* __restrict__ p4 = (const int4*)(pred + (long long)b * NPB);
  const int4* __restrict__ t4 = (const int4*)(targ + (long long)b * NPB);

  const int base = blockIdx.x * (THREADS * VECS_PER_THREAD);

  unsigned int accP = 0, accT = 0, accI = 0;

#define ACC_ELEM(PE, TE)                                 \
  {                                                      \
    const unsigned sp = 6u * (unsigned)(PE);             \
    const unsigned st = 6u * (unsigned)(TE);             \
    const unsigned op = 1u << sp;                        \
    accP += op;                                          \
    accT += 1u << st;                                    \
    accI += ((PE) == (TE)) ? op : 0u;                    \
  }

#pragma unroll
  for (int k = 0; k < VECS_PER_THREAD; ++k) {
    const int idx = base + k * THREADS + threadIdx.x;
    const int4 pv = p4[idx];
    const int4 tv = t4[idx];
    ACC_ELEM(pv.x, tv.x)
    ACC_ELEM(pv.y, tv.y)
    ACC_ELEM(pv.z, tv.z)
    ACC_ELEM(pv.w, tv.w)
  }

  // Unpack 6-bit fields -> 16-bit pairs (3 regs per counter set).
  unsigned p01 = (accP & 63u) | (((accP >> 6) & 63u) << 16);
  unsigned p23 = ((accP >> 12) & 63u) | (((accP >> 18) & 63u) << 16);
  unsigned p4r = (accP >> 24) & 63u;
  unsigned t01 = (accT & 63u) | (((accT >> 6) & 63u) << 16);
  unsigned t23 = ((accT >> 12) & 63u) | (((accT >> 18) & 63u) << 16);
  unsigned t4r = (accT >> 24) & 63u;
  unsigned i01 = (accI & 63u) | (((accI >> 6) & 63u) << 16);
  unsigned i23 = ((accI >> 12) & 63u) | (((accI >> 18) & 63u) << 16);
  unsigned i4r = (accI >> 24) & 63u;

  // 64-lane butterfly; 16-bit fields hold <= 32*64 = 2048, no overflow.
#pragma unroll
  for (int off = 32; off >= 1; off >>= 1) {
    p01 += (unsigned)__shfl_xor((int)p01, off);
    p23 += (unsigned)__shfl_xor((int)p23, off);
    p4r += (unsigned)__shfl_xor((int)p4r, off);
    t01 += (unsigned)__shfl_xor((int)t01, off);
    t23 += (unsigned)__shfl_xor((int)t23, off);
    t4r += (unsigned)__shfl_xor((int)t4r, off);
    i01 += (unsigned)__shfl_xor((int)i01, off);
    i23 += (unsigned)__shfl_xor((int)i23, off);
    i4r += (unsigned)__shfl_xor((int)i4r, off);
  }

  __shared__ unsigned int s[SLOTS];
  if (threadIdx.x < SLOTS) s[threadIdx.x] = 0;
  __syncthreads();

  if ((threadIdx.x & 63) == 0) {
    atomicAdd(&s[0], p01 & 0xFFFFu);
    atomicAdd(&s[1], p01 >> 16);
    atomicAdd(&s[2], p23 & 0xFFFFu);
    atomicAdd(&s[3], p23 >> 16);
    atomicAdd(&s[4], p4r);
    atomicAdd(&s[5], t01 & 0xFFFFu);
    atomicAdd(&s[6], t01 >> 16);
    atomicAdd(&s[7], t23 & 0xFFFFu);
    atomicAdd(&s[8], t23 >> 16);
    atomicAdd(&s[9], t4r);
    atomicAdd(&s[10], i01 & 0xFFFFu);
    atomicAdd(&s[11], i01 >> 16);
    atomicAdd(&s[12], i23 & 0xFFFFu);
    atomicAdd(&s[13], i23 >> 16);
    atomicAdd(&s[14], i4r);
  }
  __syncthreads();

  if (threadIdx.x < SLOTS)
    atomicAdd(&cnt[b * SLOTS + threadIdx.x], s[threadIdx.x]);
}

__global__ void dice_final_kernel(const unsigned int* __restrict__ cnt,
                                  float* __restrict__ out) {
  const int c = threadIdx.x;
  if (c < NUM_CLASSES) {
    float acc = 0.0f;
#pragma unroll
    for (int b = 0; b < BATCH; ++b) {
      const float ps = (float)cnt[b * SLOTS + c];
      const float ts = (float)cnt[b * SLOTS + 5 + c];
      const float is = (float)cnt[b * SLOTS + 10 + c];
      float num = 2.0f * is;
      float den = ps + ts;
      if (den == 0.0f) { num = 1.0f; den = 1.0f; }
      acc += num / den;
    }
    out[c] = acc * (1.0f / BATCH);
  }
}

extern "C" void kernel_launch(void* const* d_in, const int* in_sizes, int n_in,
                              void* d_out, int out_size, void* d_ws, size_t ws_size,
                              hipStream_t stream) {
  const int* pred = (const int*)d_in[0];
  const int* targ = (const int*)d_in[1];
  float* out = (float*)d_out;
  unsigned int* cnt = (unsigned int*)d_ws;

  hipMemsetAsync(cnt, 0, BATCH * SLOTS * sizeof(unsigned int), stream);

  dim3 grid(BLOCKS_X, BATCH);
  dice_count_kernel<<<grid, THREADS, 0, stream>>>(pred, targ, cnt);
  dice_final_kernel<<<1, 64, 0, stream>>>(cnt, out);
}